// Round 1
// baseline (877.056 us; speedup 1.0000x reference)
//
#include <hip/hip_runtime.h>

#define HID 128
#define BN_EPS 1e-5f

// ---------------- degree accumulation (counts via f32 atomics, exact) --------
__global__ __launch_bounds__(256) void k_degree(const int* __restrict__ src,
                                                const int* __restrict__ dst,
                                                float* deg, int E, int N) {
  const int stride = gridDim.x * blockDim.x;
  for (int i = blockIdx.x * blockDim.x + threadIdx.x; i < E; i += stride) {
    atomicAdd(&deg[src[i]], 1.0f);
    atomicAdd(&deg[N + dst[i]], 1.0f);
  }
}

// deg -> rsqrt(max(deg,1)) in place (works on the concatenated 2N array)
__global__ __launch_bounds__(256) void k_norm(float* deg, int total) {
  int i = blockIdx.x * blockDim.x + threadIdx.x;
  if (i < total) {
    float d = deg[i];
    deg[i] = rsqrtf(fmaxf(d, 1.0f));
  }
}

// ---------------- OUT[row,:] = scale[row] * (X[row,:] @ W) -------------------
// thread j holds W[:,j] in 128 VGPRs; x row comes in as uniform-address float4
// broadcasts (1 VMEM instr serves the whole wave).
__global__ __launch_bounds__(128) void k_gemm_rowscale(const float* __restrict__ X,
                                                       const float* __restrict__ W,
                                                       const float* __restrict__ scale,
                                                       float* __restrict__ OUT, int n) {
  const int j = threadIdx.x;
  float wreg[HID];
#pragma unroll
  for (int k = 0; k < HID; ++k) wreg[k] = W[k * HID + j];
  for (int row = blockIdx.x; row < n; row += gridDim.x) {
    const float4* xr = reinterpret_cast<const float4*>(X + (size_t)row * HID);
    float a0 = 0.f, a1 = 0.f, a2 = 0.f, a3 = 0.f;
#pragma unroll
    for (int k4 = 0; k4 < HID / 4; ++k4) {
      float4 xv = xr[k4];
      a0 = fmaf(xv.x, wreg[4 * k4 + 0], a0);
      a1 = fmaf(xv.y, wreg[4 * k4 + 1], a1);
      a2 = fmaf(xv.z, wreg[4 * k4 + 2], a2);
      a3 = fmaf(xv.w, wreg[4 * k4 + 3], a3);
    }
    OUT[(size_t)row * HID + j] = ((a0 + a1) + (a2 + a3)) * scale[row];
  }
}

// ---------------- AGG[dst,:] += H[src,:] (scatter-add) -----------------------
__global__ __launch_bounds__(256) void k_scatter(const float* __restrict__ H,
                                                 const int* __restrict__ src,
                                                 const int* __restrict__ dst,
                                                 float* AGG, int E) {
  const int j = threadIdx.x & (HID - 1);
  const int slot = threadIdx.x >> 7;  // 2 edges per block
  const int estride = gridDim.x * 2;
  for (int e = blockIdx.x * 2 + slot; e < E; e += estride) {
    int s = src[e];
    int d = dst[e];
    float v = H[(size_t)s * HID + j];
    atomicAdd(&AGG[(size_t)d * HID + j], v);
  }
}

// ---------------- OUT = AGG*norm_dst + bias; accumulate col sum/sumsq --------
// (AGG and OUT may alias: each thread reads then writes the same element)
__global__ __launch_bounds__(256) void k_finish_stats(const float* AGG,
                                                      const float* __restrict__ norm_dst,
                                                      const float* __restrict__ bias,
                                                      float* OUT, float* stats, int n) {
  const int j = threadIdx.x & (HID - 1);
  const int slot = threadIdx.x >> 7;
  const int rstride = gridDim.x * 2;
  float s = 0.f, sq = 0.f;
  float bj = bias[j];
  for (int i = blockIdx.x * 2 + slot; i < n; i += rstride) {
    float v = AGG[(size_t)i * HID + j] * norm_dst[i] + bj;
    OUT[(size_t)i * HID + j] = v;
    s += v;
    sq += v * v;
  }
  atomicAdd(&stats[j], s);
  atomicAdd(&stats[HID + j], sq);
}

// ---------------- BatchNorm (biased var) + PReLU, in place -------------------
__global__ __launch_bounds__(256) void k_bn_prelu(float* H, const float* __restrict__ stats,
                                                  const float* __restrict__ gamma,
                                                  const float* __restrict__ beta,
                                                  const float* __restrict__ a, int total4,
                                                  float invN) {
  const float slope = a[0];
  const int stride = gridDim.x * blockDim.x;
  for (int i = blockIdx.x * blockDim.x + threadIdx.x; i < total4; i += stride) {
    int j4 = i & (HID / 4 - 1);
    float4 sm = reinterpret_cast<const float4*>(stats)[j4];
    float4 sq = reinterpret_cast<const float4*>(stats + HID)[j4];
    float4 g = reinterpret_cast<const float4*>(gamma)[j4];
    float4 b = reinterpret_cast<const float4*>(beta)[j4];
    float4 v = reinterpret_cast<float4*>(H)[i];
    float m, var, t;
    m = sm.x * invN; var = sq.x * invN - m * m;
    t = (v.x - m) * rsqrtf(var + BN_EPS) * g.x + b.x;
    v.x = t >= 0.f ? t : slope * t;
    m = sm.y * invN; var = sq.y * invN - m * m;
    t = (v.y - m) * rsqrtf(var + BN_EPS) * g.y + b.y;
    v.y = t >= 0.f ? t : slope * t;
    m = sm.z * invN; var = sq.z * invN - m * m;
    t = (v.z - m) * rsqrtf(var + BN_EPS) * g.z + b.z;
    v.z = t >= 0.f ? t : slope * t;
    m = sm.w * invN; var = sq.w * invN - m * m;
    t = (v.w - m) * rsqrtf(var + BN_EPS) * g.w + b.w;
    v.w = t >= 0.f ? t : slope * t;
    reinterpret_cast<float4*>(H)[i] = v;
  }
}

extern "C" void kernel_launch(void* const* d_in, const int* in_sizes, int n_in,
                              void* d_out, int out_size, void* d_ws, size_t ws_size,
                              hipStream_t stream) {
  const float* X     = (const float*)d_in[0];
  const float* W1    = (const float*)d_in[1];
  const float* b1    = (const float*)d_in[2];
  const float* g1    = (const float*)d_in[3];
  const float* be1   = (const float*)d_in[4];
  const float* a1    = (const float*)d_in[5];
  const float* W2    = (const float*)d_in[6];
  const float* b2    = (const float*)d_in[7];
  const float* g2    = (const float*)d_in[8];
  const float* be2   = (const float*)d_in[9];
  const float* a2    = (const float*)d_in[10];
  const int*   ei    = (const int*)d_in[11];

  const int N = in_sizes[0] / HID;
  const int E = in_sizes[11] / 2;
  const int* src = ei;
  const int* dst = ei + E;

  float* out = (float*)d_out;
  float* HB = (float*)d_ws;                       // N*HID floats
  float* NS = HB + (size_t)N * HID;               // norm_src (deg_out), N floats
  float* ND = NS + N;                             // norm_dst (deg_in), N floats
  float* ST = ND + N;                             // stats: 2 layers x 256 floats

  const float invN = 1.0f / (float)N;
  const int total4 = N * (HID / 4);

  // zero degree + stats region, and the scatter destination buffer
  hipMemsetAsync(NS, 0, (size_t)(2 * N + 512) * sizeof(float), stream);
  hipMemsetAsync(HB, 0, (size_t)N * HID * sizeof(float), stream);

  k_degree<<<1024, 256, 0, stream>>>(src, dst, NS, E, N);
  k_norm<<<(2 * N + 255) / 256, 256, 0, stream>>>(NS, 2 * N);

  // ---- layer 1 ----
  k_gemm_rowscale<<<2048, 128, 0, stream>>>(X, W1, NS, out, N);      // out = (x*ns)@W1
  k_scatter<<<8192, 256, 0, stream>>>(out, src, dst, HB, E);         // HB = A@out
  k_finish_stats<<<1024, 256, 0, stream>>>(HB, ND, b1, HB, ST, N);   // HB = HB*nd + b1
  k_bn_prelu<<<2048, 256, 0, stream>>>(HB, ST, g1, be1, a1, total4, invN);

  // ---- layer 2 ----
  k_gemm_rowscale<<<2048, 128, 0, stream>>>(HB, W2, NS, out, N);     // out = (h*ns)@W2
  hipMemsetAsync(HB, 0, (size_t)N * HID * sizeof(float), stream);
  k_scatter<<<8192, 256, 0, stream>>>(out, src, dst, HB, E);         // HB = A@out
  k_finish_stats<<<1024, 256, 0, stream>>>(HB, ND, b2, out, ST + 256, N);
  k_bn_prelu<<<2048, 256, 0, stream>>>(out, ST + 256, g2, be2, a2, total4, invN);
}

// Round 2
// 856.358 us; speedup vs baseline: 1.0242x; 1.0242x over previous
//
#include <hip/hip_runtime.h>

#define HID 128
#define BN_EPS 1e-5f

// ---------------- degree histogram (int atomics): deg[0:N)=out(src), deg[N:2N)=in(dst)
__global__ __launch_bounds__(256) void k_hist(const int* __restrict__ src,
                                              const int* __restrict__ dst,
                                              int* deg, int E, int N) {
  const int stride = gridDim.x * blockDim.x;
  for (int i = blockIdx.x * blockDim.x + threadIdx.x; i < E; i += stride) {
    atomicAdd(&deg[src[i]], 1);
    atomicAdd(&deg[N + dst[i]], 1);
  }
}

// ---------------- norms: NSND[i] = rsqrt(max(deg[i],1)) for all 2N ----------
__global__ __launch_bounds__(256) void k_norm(const int* __restrict__ deg,
                                              float* __restrict__ nsnd, int total) {
  int i = blockIdx.x * blockDim.x + threadIdx.x;
  if (i < total) nsnd[i] = rsqrtf(fmaxf((float)deg[i], 1.0f));
}

// ---------------- single-block exclusive scan of in-degrees -> offsets, cursor
__global__ __launch_bounds__(1024) void k_scan(const int* __restrict__ deg,
                                               int* __restrict__ offsets,
                                               int* __restrict__ cursor, int n) {
  __shared__ int lsum[1024];
  const int t = threadIdx.x;
  const int ch = (n + 1023) >> 10;
  const int lo = t * ch;
  const int hi = min(n, lo + ch);
  int s = 0;
  for (int i = lo; i < hi; ++i) s += deg[i];
  lsum[t] = s;
  __syncthreads();
  // Hillis-Steele inclusive scan over 1024 partials
  for (int off = 1; off < 1024; off <<= 1) {
    int v = lsum[t];
    int add = (t >= off) ? lsum[t - off] : 0;
    __syncthreads();
    lsum[t] = v + add;
    __syncthreads();
  }
  int run = (t == 0) ? 0 : lsum[t - 1];  // exclusive prefix of this chunk
  for (int i = lo; i < hi; ++i) {
    offsets[i] = run;
    cursor[i] = run;
    run += deg[i];
  }
  if (t == 1023) offsets[n] = lsum[1023];
}

// ---------------- CSC fill: csc[pos] = src, pos from per-dst cursor ----------
__global__ __launch_bounds__(256) void k_fill(const int* __restrict__ src,
                                              const int* __restrict__ dst,
                                              int* cursor, int* __restrict__ csc, int E) {
  const int stride = gridDim.x * blockDim.x;
  for (int i = blockIdx.x * blockDim.x + threadIdx.x; i < E; i += stride) {
    int d = dst[i];
    int pos = atomicAdd(&cursor[d], 1);
    csc[pos] = src[i];
  }
}

// ---------------- OUT[row,:] = scale[row] * (X[row,:] @ W) -------------------
__global__ __launch_bounds__(128) void k_gemm_rowscale(const float* __restrict__ X,
                                                       const float* __restrict__ W,
                                                       const float* __restrict__ scale,
                                                       float* __restrict__ OUT, int n) {
  const int j = threadIdx.x;
  float wreg[HID];
#pragma unroll
  for (int k = 0; k < HID; ++k) wreg[k] = W[k * HID + j];
  for (int row = blockIdx.x; row < n; row += gridDim.x) {
    const float4* xr = reinterpret_cast<const float4*>(X + (size_t)row * HID);
    float a0 = 0.f, a1 = 0.f, a2 = 0.f, a3 = 0.f;
#pragma unroll
    for (int k4 = 0; k4 < HID / 4; ++k4) {
      float4 xv = xr[k4];
      a0 = fmaf(xv.x, wreg[4 * k4 + 0], a0);
      a1 = fmaf(xv.y, wreg[4 * k4 + 1], a1);
      a2 = fmaf(xv.z, wreg[4 * k4 + 2], a2);
      a3 = fmaf(xv.w, wreg[4 * k4 + 3], a3);
    }
    OUT[(size_t)row * HID + j] = ((a0 + a1) + (a2 + a3)) * scale[row];
  }
}

// ---------------- gather-aggregate + finish + stats --------------------------
// OUT[i,:] = (sum_{e in CSC[i]} H[csc[e],:]) * nd[i] + bias ; accumulate col stats
__global__ __launch_bounds__(256) void k_agg_finish(const float* __restrict__ H,
                                                    const int* __restrict__ offsets,
                                                    const int* __restrict__ csc,
                                                    const float* __restrict__ nd,
                                                    const float* __restrict__ bias,
                                                    float* __restrict__ OUT,
                                                    float* stats, int n) {
  const int j = threadIdx.x & (HID - 1);
  const int slot = threadIdx.x >> 7;  // 2 rows per block per iteration
  const int rstride = gridDim.x * 2;
  const float bj = bias[j];
  float s = 0.f, sq = 0.f;
  for (int i = blockIdx.x * 2 + slot; i < n; i += rstride) {
    const int e0 = offsets[i];
    const int e1 = offsets[i + 1];
    float acc = 0.f;
    for (int e = e0; e < e1; ++e) {
      int sidx = csc[e];
      acc += H[(size_t)sidx * HID + j];
    }
    float v = acc * nd[i] + bj;
    OUT[(size_t)i * HID + j] = v;
    s += v;
    sq += v * v;
  }
  atomicAdd(&stats[j], s);
  atomicAdd(&stats[HID + j], sq);
}

// ---------------- BatchNorm (biased var) + PReLU -----------------------------
__global__ __launch_bounds__(256) void k_bn_prelu(const float* __restrict__ IN, float* __restrict__ OUT,
                                                  const float* __restrict__ stats,
                                                  const float* __restrict__ gamma,
                                                  const float* __restrict__ beta,
                                                  const float* __restrict__ a, int total4,
                                                  float invN) {
  const float slope = a[0];
  const int stride = gridDim.x * blockDim.x;
  for (int i = blockIdx.x * blockDim.x + threadIdx.x; i < total4; i += stride) {
    int j4 = i & (HID / 4 - 1);
    float4 sm = reinterpret_cast<const float4*>(stats)[j4];
    float4 sq = reinterpret_cast<const float4*>(stats + HID)[j4];
    float4 g = reinterpret_cast<const float4*>(gamma)[j4];
    float4 b = reinterpret_cast<const float4*>(beta)[j4];
    float4 v = reinterpret_cast<const float4*>(IN)[i];
    float m, var, t;
    m = sm.x * invN; var = sq.x * invN - m * m;
    t = (v.x - m) * rsqrtf(var + BN_EPS) * g.x + b.x;
    v.x = t >= 0.f ? t : slope * t;
    m = sm.y * invN; var = sq.y * invN - m * m;
    t = (v.y - m) * rsqrtf(var + BN_EPS) * g.y + b.y;
    v.y = t >= 0.f ? t : slope * t;
    m = sm.z * invN; var = sq.z * invN - m * m;
    t = (v.z - m) * rsqrtf(var + BN_EPS) * g.z + b.z;
    v.z = t >= 0.f ? t : slope * t;
    m = sm.w * invN; var = sq.w * invN - m * m;
    t = (v.w - m) * rsqrtf(var + BN_EPS) * g.w + b.w;
    v.w = t >= 0.f ? t : slope * t;
    reinterpret_cast<float4*>(OUT)[i] = v;
  }
}

extern "C" void kernel_launch(void* const* d_in, const int* in_sizes, int n_in,
                              void* d_out, int out_size, void* d_ws, size_t ws_size,
                              hipStream_t stream) {
  const float* X   = (const float*)d_in[0];
  const float* W1  = (const float*)d_in[1];
  const float* b1  = (const float*)d_in[2];
  const float* g1  = (const float*)d_in[3];
  const float* be1 = (const float*)d_in[4];
  const float* a1  = (const float*)d_in[5];
  const float* W2  = (const float*)d_in[6];
  const float* b2  = (const float*)d_in[7];
  const float* g2  = (const float*)d_in[8];
  const float* be2 = (const float*)d_in[9];
  const float* a2  = (const float*)d_in[10];
  const int*   ei  = (const int*)d_in[11];

  const int N = in_sizes[0] / HID;
  const int E = in_sizes[11] / 2;
  const int* src = ei;
  const int* dst = ei + E;

  float* out = (float*)d_out;

  // workspace layout (all 4-byte units)
  float* HB      = (float*)d_ws;                    // N*HID floats
  int*   deg     = (int*)(HB + (size_t)N * HID);    // 2N ints: [0:N)=out-deg, [N:2N)=in-deg
  float* NSND    = (float*)(deg + 2 * (size_t)N);   // 2N floats: NS then ND
  float* ST      = NSND + 2 * (size_t)N;            // 512 floats (2 layers x 256)
  int*   offsets = (int*)(ST + 512);                // N+1 ints
  int*   csc     = offsets + N + 1;                 // E ints
  int*   cursor  = deg;                             // aliases out-deg region (free after k_norm)

  const float invN = 1.0f / (float)N;
  const int total4 = N * (HID / 4);

  hipMemsetAsync(deg, 0, 2 * (size_t)N * sizeof(int), stream);
  hipMemsetAsync(ST, 0, 512 * sizeof(float), stream);

  // graph preprocessing (once, reused by both layers)
  k_hist<<<1024, 256, 0, stream>>>(src, dst, deg, E, N);
  k_norm<<<(2 * N + 255) / 256, 256, 0, stream>>>(deg, NSND, 2 * N);
  k_scan<<<1, 1024, 0, stream>>>(deg + N, offsets, cursor, N);
  k_fill<<<1024, 256, 0, stream>>>(src, dst, cursor, csc, E);

  // ---- layer 1 ----
  k_gemm_rowscale<<<2048, 128, 0, stream>>>(X, W1, NSND, out, N);
  k_agg_finish<<<4096, 256, 0, stream>>>(out, offsets, csc, NSND + N, b1, HB, ST, N);
  k_bn_prelu<<<2048, 256, 0, stream>>>(HB, HB, ST, g1, be1, a1, total4, invN);

  // ---- layer 2 ----
  k_gemm_rowscale<<<2048, 128, 0, stream>>>(HB, W2, NSND, out, N);
  k_agg_finish<<<4096, 256, 0, stream>>>(out, offsets, csc, NSND + N, b2, HB, ST + 256, N);
  k_bn_prelu<<<2048, 256, 0, stream>>>(HB, out, ST + 256, g2, be2, a2, total4, invN);
}

// Round 3
// 494.317 us; speedup vs baseline: 1.7743x; 1.7324x over previous
//
#include <hip/hip_runtime.h>

#define HID 128
#define BN_EPS 1e-5f

// ---------------- degree histogram (int atomics): deg[0:N)=out(src), deg[N:2N)=in(dst)
__global__ __launch_bounds__(256) void k_hist(const int* __restrict__ src,
                                              const int* __restrict__ dst,
                                              int* deg, int E, int N) {
  const int stride = gridDim.x * blockDim.x;
  for (int i = blockIdx.x * blockDim.x + threadIdx.x; i < E; i += stride) {
    atomicAdd(&deg[src[i]], 1);
    atomicAdd(&deg[N + dst[i]], 1);
  }
}

// ---------------- norms: NSND[i] = rsqrt(max(deg[i],1)) for all 2N ----------
__global__ __launch_bounds__(256) void k_norm(const int* __restrict__ deg,
                                              float* __restrict__ nsnd, int total) {
  int i = blockIdx.x * blockDim.x + threadIdx.x;
  if (i < total) nsnd[i] = rsqrtf(fmaxf((float)deg[i], 1.0f));
}

// ---------------- single-block exclusive scan of in-degrees -> offsets, cursor
__global__ __launch_bounds__(1024) void k_scan(const int* __restrict__ deg,
                                               int* __restrict__ offsets,
                                               int* __restrict__ cursor, int n) {
  __shared__ int lsum[1024];
  const int t = threadIdx.x;
  const int ch = (n + 1023) >> 10;
  const int lo = t * ch;
  const int hi = min(n, lo + ch);
  int s = 0;
  for (int i = lo; i < hi; ++i) s += deg[i];
  lsum[t] = s;
  __syncthreads();
  for (int off = 1; off < 1024; off <<= 1) {
    int v = lsum[t];
    int add = (t >= off) ? lsum[t - off] : 0;
    __syncthreads();
    lsum[t] = v + add;
    __syncthreads();
  }
  int run = (t == 0) ? 0 : lsum[t - 1];
  for (int i = lo; i < hi; ++i) {
    offsets[i] = run;
    cursor[i] = run;
    run += deg[i];
  }
  if (t == 1023) offsets[n] = lsum[1023];
}

// ---------------- CSC fill: csc[pos] = src, pos from per-dst cursor ----------
__global__ __launch_bounds__(256) void k_fill(const int* __restrict__ src,
                                              const int* __restrict__ dst,
                                              int* cursor, int* __restrict__ csc, int E) {
  const int stride = gridDim.x * blockDim.x;
  for (int i = blockIdx.x * blockDim.x + threadIdx.x; i < E; i += stride) {
    int d = dst[i];
    int pos = atomicAdd(&cursor[d], 1);
    csc[pos] = src[i];
  }
}

// ---------------- OUT[row,:] = scale[row] * (X[row,:] @ W) -------------------
__global__ __launch_bounds__(128) void k_gemm_rowscale(const float* __restrict__ X,
                                                       const float* __restrict__ W,
                                                       const float* __restrict__ scale,
                                                       float* __restrict__ OUT, int n) {
  const int j = threadIdx.x;
  float wreg[HID];
#pragma unroll
  for (int k = 0; k < HID; ++k) wreg[k] = W[k * HID + j];
  for (int row = blockIdx.x; row < n; row += gridDim.x) {
    const float4* xr = reinterpret_cast<const float4*>(X + (size_t)row * HID);
    float a0 = 0.f, a1 = 0.f, a2 = 0.f, a3 = 0.f;
#pragma unroll
    for (int k4 = 0; k4 < HID / 4; ++k4) {
      float4 xv = xr[k4];
      a0 = fmaf(xv.x, wreg[4 * k4 + 0], a0);
      a1 = fmaf(xv.y, wreg[4 * k4 + 1], a1);
      a2 = fmaf(xv.z, wreg[4 * k4 + 2], a2);
      a3 = fmaf(xv.w, wreg[4 * k4 + 3], a3);
    }
    OUT[(size_t)row * HID + j] = ((a0 + a1) + (a2 + a3)) * scale[row];
  }
}

// ---------------- gather-aggregate + finish + stats (MLP-optimized) ----------
// 32 lanes (float4 each) per row; 8 rows per 256-block; edge chunks of 8 with
// prefetched indices so ~8 row-gathers are in flight per row-group.
#define CHUNK 8
__global__ __launch_bounds__(256) void k_agg_finish(const float* __restrict__ H,
                                                    const int* __restrict__ offsets,
                                                    const int* __restrict__ csc,
                                                    const float* __restrict__ nd,
                                                    const float* __restrict__ bias,
                                                    float* __restrict__ OUT,
                                                    float* stats, int n) {
  const int lane = threadIdx.x & 31;   // feature-quad index (features 4*lane..4*lane+3)
  const int slot = threadIdx.x >> 5;   // 8 row-groups per block
  const int rstride = gridDim.x * 8;
  const float4 bj = reinterpret_cast<const float4*>(bias)[lane];
  float4 s = {0.f, 0.f, 0.f, 0.f}, sq = {0.f, 0.f, 0.f, 0.f};

  for (int i = blockIdx.x * 8 + slot; i < n; i += rstride) {
    const int e0 = offsets[i];
    const int e1 = offsets[i + 1];
    float4 acc = {0.f, 0.f, 0.f, 0.f};
    for (int e = e0; e < e1; e += CHUNK) {
      int idx[CHUNK];
#pragma unroll
      for (int k = 0; k < CHUNK; ++k) idx[k] = csc[min(e + k, e1 - 1)];
      float4 v[CHUNK];
#pragma unroll
      for (int k = 0; k < CHUNK; ++k)
        v[k] = reinterpret_cast<const float4*>(H + (size_t)idx[k] * HID)[lane];
#pragma unroll
      for (int k = 0; k < CHUNK; ++k) {
        if (e + k < e1) {
          acc.x += v[k].x; acc.y += v[k].y; acc.z += v[k].z; acc.w += v[k].w;
        }
      }
    }
    const float ndv = nd[i];
    float4 o;
    o.x = acc.x * ndv + bj.x;
    o.y = acc.y * ndv + bj.y;
    o.z = acc.z * ndv + bj.z;
    o.w = acc.w * ndv + bj.w;
    reinterpret_cast<float4*>(OUT + (size_t)i * HID)[lane] = o;
    s.x += o.x; s.y += o.y; s.z += o.z; s.w += o.w;
    sq.x += o.x * o.x; sq.y += o.y * o.y; sq.z += o.z * o.z; sq.w += o.w * o.w;
  }

  // block-level stats reduction: 8 slots -> 1, then 256 atomics per block
  __shared__ float red[2][8][HID];
  *reinterpret_cast<float4*>(&red[0][slot][lane * 4]) = s;
  *reinterpret_cast<float4*>(&red[1][slot][lane * 4]) = sq;
  __syncthreads();
  const int t = threadIdx.x;
  if (t < HID) {
    float a = 0.f;
#pragma unroll
    for (int k = 0; k < 8; ++k) a += red[0][k][t];
    atomicAdd(&stats[t], a);
  } else {
    const int j = t - HID;
    float a = 0.f;
#pragma unroll
    for (int k = 0; k < 8; ++k) a += red[1][k][j];
    atomicAdd(&stats[HID + j], a);
  }
}

// ---------------- BatchNorm (biased var) + PReLU -----------------------------
__global__ __launch_bounds__(256) void k_bn_prelu(const float* __restrict__ IN, float* __restrict__ OUT,
                                                  const float* __restrict__ stats,
                                                  const float* __restrict__ gamma,
                                                  const float* __restrict__ beta,
                                                  const float* __restrict__ a, int total4,
                                                  float invN) {
  const float slope = a[0];
  const int stride = gridDim.x * blockDim.x;
  for (int i = blockIdx.x * blockDim.x + threadIdx.x; i < total4; i += stride) {
    int j4 = i & (HID / 4 - 1);
    float4 sm = reinterpret_cast<const float4*>(stats)[j4];
    float4 sq = reinterpret_cast<const float4*>(stats + HID)[j4];
    float4 g = reinterpret_cast<const float4*>(gamma)[j4];
    float4 b = reinterpret_cast<const float4*>(beta)[j4];
    float4 v = reinterpret_cast<const float4*>(IN)[i];
    float m, var, t;
    m = sm.x * invN; var = sq.x * invN - m * m;
    t = (v.x - m) * rsqrtf(var + BN_EPS) * g.x + b.x;
    v.x = t >= 0.f ? t : slope * t;
    m = sm.y * invN; var = sq.y * invN - m * m;
    t = (v.y - m) * rsqrtf(var + BN_EPS) * g.y + b.y;
    v.y = t >= 0.f ? t : slope * t;
    m = sm.z * invN; var = sq.z * invN - m * m;
    t = (v.z - m) * rsqrtf(var + BN_EPS) * g.z + b.z;
    v.z = t >= 0.f ? t : slope * t;
    m = sm.w * invN; var = sq.w * invN - m * m;
    t = (v.w - m) * rsqrtf(var + BN_EPS) * g.w + b.w;
    v.w = t >= 0.f ? t : slope * t;
    reinterpret_cast<float4*>(OUT)[i] = v;
  }
}

extern "C" void kernel_launch(void* const* d_in, const int* in_sizes, int n_in,
                              void* d_out, int out_size, void* d_ws, size_t ws_size,
                              hipStream_t stream) {
  const float* X   = (const float*)d_in[0];
  const float* W1  = (const float*)d_in[1];
  const float* b1  = (const float*)d_in[2];
  const float* g1  = (const float*)d_in[3];
  const float* be1 = (const float*)d_in[4];
  const float* a1  = (const float*)d_in[5];
  const float* W2  = (const float*)d_in[6];
  const float* b2  = (const float*)d_in[7];
  const float* g2  = (const float*)d_in[8];
  const float* be2 = (const float*)d_in[9];
  const float* a2  = (const float*)d_in[10];
  const int*   ei  = (const int*)d_in[11];

  const int N = in_sizes[0] / HID;
  const int E = in_sizes[11] / 2;
  const int* src = ei;
  const int* dst = ei + E;

  float* out = (float*)d_out;

  // workspace layout (all 4-byte units)
  float* HB      = (float*)d_ws;                    // N*HID floats
  int*   deg     = (int*)(HB + (size_t)N * HID);    // 2N ints
  float* NSND    = (float*)(deg + 2 * (size_t)N);   // 2N floats: NS then ND
  float* ST      = NSND + 2 * (size_t)N;            // 512 floats
  int*   offsets = (int*)(ST + 512);                // N+1 ints
  int*   csc     = offsets + N + 1;                 // E ints
  int*   cursor  = deg;                             // aliases out-deg (free after k_norm)

  const float invN = 1.0f / (float)N;
  const int total4 = N * (HID / 4);

  hipMemsetAsync(deg, 0, 2 * (size_t)N * sizeof(int), stream);
  hipMemsetAsync(ST, 0, 512 * sizeof(float), stream);

  // graph preprocessing (once, reused by both layers)
  k_hist<<<1024, 256, 0, stream>>>(src, dst, deg, E, N);
  k_norm<<<(2 * N + 255) / 256, 256, 0, stream>>>(deg, NSND, 2 * N);
  k_scan<<<1, 1024, 0, stream>>>(deg + N, offsets, cursor, N);
  k_fill<<<1024, 256, 0, stream>>>(src, dst, cursor, csc, E);

  // ---- layer 1 ----
  k_gemm_rowscale<<<2048, 128, 0, stream>>>(X, W1, NSND, out, N);
  k_agg_finish<<<1024, 256, 0, stream>>>(out, offsets, csc, NSND + N, b1, HB, ST, N);
  k_bn_prelu<<<2048, 256, 0, stream>>>(HB, HB, ST, g1, be1, a1, total4, invN);

  // ---- layer 2 ----
  k_gemm_rowscale<<<2048, 128, 0, stream>>>(HB, W2, NSND, out, N);
  k_agg_finish<<<1024, 256, 0, stream>>>(out, offsets, csc, NSND + N, b2, HB, ST + 256, N);
  k_bn_prelu<<<2048, 256, 0, stream>>>(HB, out, ST + 256, g2, be2, a2, total4, invN);
}

// Round 4
// 394.805 us; speedup vs baseline: 2.2215x; 1.2521x over previous
//
#include <hip/hip_runtime.h>

#define HID 128
#define BN_EPS 1e-5f

// ---------------- degree histogram (int atomics): deg[0:N)=out(src), deg[N:2N)=in(dst)
__global__ __launch_bounds__(256) void k_hist(const int* __restrict__ src,
                                              const int* __restrict__ dst,
                                              int* deg, int E, int N) {
  const int stride = gridDim.x * blockDim.x;
  for (int i = blockIdx.x * blockDim.x + threadIdx.x; i < E; i += stride) {
    atomicAdd(&deg[src[i]], 1);
    atomicAdd(&deg[N + dst[i]], 1);
  }
}

// ---------------- norms: NSND[i] = rsqrt(max(deg[i],1)) for all 2N ----------
__global__ __launch_bounds__(256) void k_norm(const int* __restrict__ deg,
                                              float* __restrict__ nsnd, int total) {
  int i = blockIdx.x * blockDim.x + threadIdx.x;
  if (i < total) nsnd[i] = rsqrtf(fmaxf((float)deg[i], 1.0f));
}

// ---------------- parallel scan, pass 1: per-block sums ----------------------
__global__ __launch_bounds__(256) void k_scan_part(const int* __restrict__ deg,
                                                   int* __restrict__ bsum, int n) {
  __shared__ int red[256];
  const int t = threadIdx.x;
  const int i = blockIdx.x * 256 + t;
  red[t] = (i < n) ? deg[i] : 0;
  __syncthreads();
  for (int off = 128; off > 0; off >>= 1) {
    if (t < off) red[t] += red[t + off];
    __syncthreads();
  }
  if (t == 0) bsum[blockIdx.x] = red[0];
}

// ---------------- pass 2: exclusive scan of block sums (nb <= 1024) ----------
__global__ __launch_bounds__(1024) void k_scan_mid(int* bsum, int nb) {
  __shared__ int l[1024];
  const int t = threadIdx.x;
  l[t] = (t < nb) ? bsum[t] : 0;
  __syncthreads();
  for (int off = 1; off < 1024; off <<= 1) {
    int v = l[t];
    int add = (t >= off) ? l[t - off] : 0;
    __syncthreads();
    l[t] = v + add;
    __syncthreads();
  }
  if (t < nb) bsum[t] = (t == 0) ? 0 : l[t - 1];
}

// ---------------- pass 3: local scan + global offset write -------------------
__global__ __launch_bounds__(256) void k_scan_out(const int* __restrict__ deg,
                                                  const int* __restrict__ bpre,
                                                  int* __restrict__ offsets,
                                                  int* __restrict__ cursor, int n) {
  __shared__ int l[256];
  const int t = threadIdx.x;
  const int i = blockIdx.x * 256 + t;
  const int v = (i < n) ? deg[i] : 0;
  l[t] = v;
  __syncthreads();
  for (int off = 1; off < 256; off <<= 1) {
    int x = l[t];
    int add = (t >= off) ? l[t - off] : 0;
    __syncthreads();
    l[t] = x + add;
    __syncthreads();
  }
  const int excl = bpre[blockIdx.x] + l[t] - v;
  if (i < n) {
    offsets[i] = excl;
    cursor[i] = excl;
    if (i == n - 1) offsets[n] = excl + v;
  }
}

// ---------------- CSC fill: csc[pos] = src, pos from per-dst cursor ----------
__global__ __launch_bounds__(256) void k_fill(const int* __restrict__ src,
                                              const int* __restrict__ dst,
                                              int* cursor, int* __restrict__ csc, int E) {
  const int stride = gridDim.x * blockDim.x;
  for (int i = blockIdx.x * blockDim.x + threadIdx.x; i < E; i += stride) {
    int d = dst[i];
    int pos = atomicAdd(&cursor[d], 1);
    csc[pos] = src[i];
  }
}

// ---------------- OUT[row,:] = scale[row] * (X[row,:] @ W) -------------------
__global__ __launch_bounds__(128) void k_gemm_rowscale(const float* __restrict__ X,
                                                       const float* __restrict__ W,
                                                       const float* __restrict__ scale,
                                                       float* __restrict__ OUT, int n) {
  const int j = threadIdx.x;
  float wreg[HID];
#pragma unroll
  for (int k = 0; k < HID; ++k) wreg[k] = W[k * HID + j];
  for (int row = blockIdx.x; row < n; row += gridDim.x) {
    const float4* xr = reinterpret_cast<const float4*>(X + (size_t)row * HID);
    float a0 = 0.f, a1 = 0.f, a2 = 0.f, a3 = 0.f;
#pragma unroll
    for (int k4 = 0; k4 < HID / 4; ++k4) {
      float4 xv = xr[k4];
      a0 = fmaf(xv.x, wreg[4 * k4 + 0], a0);
      a1 = fmaf(xv.y, wreg[4 * k4 + 1], a1);
      a2 = fmaf(xv.z, wreg[4 * k4 + 2], a2);
      a3 = fmaf(xv.w, wreg[4 * k4 + 3], a3);
    }
    OUT[(size_t)row * HID + j] = ((a0 + a1) + (a2 + a3)) * scale[row];
  }
}

// ---------------- gather-aggregate + finish + stats (MLP-optimized) ----------
#define CHUNK 8
__global__ __launch_bounds__(256) void k_agg_finish(const float* __restrict__ H,
                                                    const int* __restrict__ offsets,
                                                    const int* __restrict__ csc,
                                                    const float* __restrict__ nd,
                                                    const float* __restrict__ bias,
                                                    float* __restrict__ OUT,
                                                    float* stats, int n) {
  const int lane = threadIdx.x & 31;   // feature-quad index
  const int slot = threadIdx.x >> 5;   // 8 row-groups per block
  const int rstride = gridDim.x * 8;
  const float4 bj = reinterpret_cast<const float4*>(bias)[lane];
  float4 s = {0.f, 0.f, 0.f, 0.f}, sq = {0.f, 0.f, 0.f, 0.f};

  for (int i = blockIdx.x * 8 + slot; i < n; i += rstride) {
    const int e0 = offsets[i];
    const int e1 = offsets[i + 1];
    float4 acc = {0.f, 0.f, 0.f, 0.f};
    for (int e = e0; e < e1; e += CHUNK) {
      int idx[CHUNK];
#pragma unroll
      for (int k = 0; k < CHUNK; ++k) idx[k] = csc[min(e + k, e1 - 1)];
      float4 v[CHUNK];
#pragma unroll
      for (int k = 0; k < CHUNK; ++k)
        v[k] = reinterpret_cast<const float4*>(H + (size_t)idx[k] * HID)[lane];
#pragma unroll
      for (int k = 0; k < CHUNK; ++k) {
        if (e + k < e1) {
          acc.x += v[k].x; acc.y += v[k].y; acc.z += v[k].z; acc.w += v[k].w;
        }
      }
    }
    const float ndv = nd[i];
    float4 o;
    o.x = acc.x * ndv + bj.x;
    o.y = acc.y * ndv + bj.y;
    o.z = acc.z * ndv + bj.z;
    o.w = acc.w * ndv + bj.w;
    reinterpret_cast<float4*>(OUT + (size_t)i * HID)[lane] = o;
    s.x += o.x; s.y += o.y; s.z += o.z; s.w += o.w;
    sq.x += o.x * o.x; sq.y += o.y * o.y; sq.z += o.z * o.z; sq.w += o.w * o.w;
  }

  __shared__ float red[2][8][HID];
  *reinterpret_cast<float4*>(&red[0][slot][lane * 4]) = s;
  *reinterpret_cast<float4*>(&red[1][slot][lane * 4]) = sq;
  __syncthreads();
  const int t = threadIdx.x;
  if (t < HID) {
    float a = 0.f;
#pragma unroll
    for (int k = 0; k < 8; ++k) a += red[0][k][t];
    atomicAdd(&stats[t], a);
  } else {
    const int j = t - HID;
    float a = 0.f;
#pragma unroll
    for (int k = 0; k < 8; ++k) a += red[1][k][j];
    atomicAdd(&stats[HID + j], a);
  }
}

// ---------------- BatchNorm (biased var) + PReLU -----------------------------
__global__ __launch_bounds__(256) void k_bn_prelu(const float* __restrict__ IN, float* __restrict__ OUT,
                                                  const float* __restrict__ stats,
                                                  const float* __restrict__ gamma,
                                                  const float* __restrict__ beta,
                                                  const float* __restrict__ a, int total4,
                                                  float invN) {
  const float slope = a[0];
  const int stride = gridDim.x * blockDim.x;
  for (int i = blockIdx.x * blockDim.x + threadIdx.x; i < total4; i += stride) {
    int j4 = i & (HID / 4 - 1);
    float4 sm = reinterpret_cast<const float4*>(stats)[j4];
    float4 sq = reinterpret_cast<const float4*>(stats + HID)[j4];
    float4 g = reinterpret_cast<const float4*>(gamma)[j4];
    float4 b = reinterpret_cast<const float4*>(beta)[j4];
    float4 v = reinterpret_cast<const float4*>(IN)[i];
    float m, var, t;
    m = sm.x * invN; var = sq.x * invN - m * m;
    t = (v.x - m) * rsqrtf(var + BN_EPS) * g.x + b.x;
    v.x = t >= 0.f ? t : slope * t;
    m = sm.y * invN; var = sq.y * invN - m * m;
    t = (v.y - m) * rsqrtf(var + BN_EPS) * g.y + b.y;
    v.y = t >= 0.f ? t : slope * t;
    m = sm.z * invN; var = sq.z * invN - m * m;
    t = (v.z - m) * rsqrtf(var + BN_EPS) * g.z + b.z;
    v.z = t >= 0.f ? t : slope * t;
    m = sm.w * invN; var = sq.w * invN - m * m;
    t = (v.w - m) * rsqrtf(var + BN_EPS) * g.w + b.w;
    v.w = t >= 0.f ? t : slope * t;
    reinterpret_cast<float4*>(OUT)[i] = v;
  }
}

extern "C" void kernel_launch(void* const* d_in, const int* in_sizes, int n_in,
                              void* d_out, int out_size, void* d_ws, size_t ws_size,
                              hipStream_t stream) {
  const float* X   = (const float*)d_in[0];
  const float* W1  = (const float*)d_in[1];
  const float* b1  = (const float*)d_in[2];
  const float* g1  = (const float*)d_in[3];
  const float* be1 = (const float*)d_in[4];
  const float* a1  = (const float*)d_in[5];
  const float* W2  = (const float*)d_in[6];
  const float* b2  = (const float*)d_in[7];
  const float* g2  = (const float*)d_in[8];
  const float* be2 = (const float*)d_in[9];
  const float* a2  = (const float*)d_in[10];
  const int*   ei  = (const int*)d_in[11];

  const int N = in_sizes[0] / HID;
  const int E = in_sizes[11] / 2;
  const int* src = ei;
  const int* dst = ei + E;

  float* out = (float*)d_out;

  // workspace layout (all 4-byte units)
  float* HB      = (float*)d_ws;                    // N*HID floats
  int*   deg     = (int*)(HB + (size_t)N * HID);    // 2N ints
  float* NSND    = (float*)(deg + 2 * (size_t)N);   // 2N floats: NS then ND
  float* ST      = NSND + 2 * (size_t)N;            // 512 floats
  int*   offsets = (int*)(ST + 512);                // N+1 ints
  int*   csc     = offsets + N + 1;                 // E ints
  int*   bsum    = csc + E;                         // up to 1024 ints (block sums)
  int*   cursor  = deg;                             // aliases out-deg (free after k_norm)

  const float invN = 1.0f / (float)N;
  const int total4 = N * (HID / 4);
  const int nb = (N + 255) / 256;

  hipMemsetAsync(deg, 0, 2 * (size_t)N * sizeof(int), stream);
  hipMemsetAsync(ST, 0, 512 * sizeof(float), stream);

  // graph preprocessing (once, reused by both layers)
  k_hist<<<1024, 256, 0, stream>>>(src, dst, deg, E, N);
  k_norm<<<(2 * N + 255) / 256, 256, 0, stream>>>(deg, NSND, 2 * N);
  k_scan_part<<<nb, 256, 0, stream>>>(deg + N, bsum, N);
  k_scan_mid<<<1, 1024, 0, stream>>>(bsum, nb);
  k_scan_out<<<nb, 256, 0, stream>>>(deg + N, bsum, offsets, cursor, N);
  k_fill<<<1024, 256, 0, stream>>>(src, dst, cursor, csc, E);

  // ---- layer 1 ----
  k_gemm_rowscale<<<2048, 128, 0, stream>>>(X, W1, NSND, out, N);
  k_agg_finish<<<1024, 256, 0, stream>>>(out, offsets, csc, NSND + N, b1, HB, ST, N);
  k_bn_prelu<<<2048, 256, 0, stream>>>(HB, HB, ST, g1, be1, a1, total4, invN);

  // ---- layer 2 ----
  k_gemm_rowscale<<<2048, 128, 0, stream>>>(HB, W2, NSND, out, N);
  k_agg_finish<<<1024, 256, 0, stream>>>(out, offsets, csc, NSND + N, b2, HB, ST + 256, N);
  k_bn_prelu<<<2048, 256, 0, stream>>>(HB, out, ST + 256, g2, be2, a2, total4, invN);
}

// Round 5
// 291.333 us; speedup vs baseline: 3.0105x; 1.3552x over previous
//
#include <hip/hip_runtime.h>

#define HID 128
#define BN_EPS 1e-5f

typedef __attribute__((ext_vector_type(8))) short bf16x8;
typedef __attribute__((ext_vector_type(4))) float f32x4;

__device__ __forceinline__ float bf2f(unsigned short u) {
  union { unsigned int i; float f; } c; c.i = ((unsigned int)u) << 16; return c.f;
}
__device__ __forceinline__ unsigned short f2bf(float f) {
  union { float f; unsigned int i; } c; c.f = f;
  unsigned int u = c.i;
  return (unsigned short)((u + 0x7FFFu + ((u >> 16) & 1u)) >> 16);
}

// ---------------- degree histogram ------------------------------------------
__global__ __launch_bounds__(256) void k_hist(const int* __restrict__ src,
                                              const int* __restrict__ dst,
                                              int* deg, int E, int N) {
  const int stride = gridDim.x * blockDim.x;
  for (int i = blockIdx.x * blockDim.x + threadIdx.x; i < E; i += stride) {
    atomicAdd(&deg[src[i]], 1);
    atomicAdd(&deg[N + dst[i]], 1);
  }
}

__global__ __launch_bounds__(256) void k_norm(const int* __restrict__ deg,
                                              float* __restrict__ nsnd, int total) {
  int i = blockIdx.x * blockDim.x + threadIdx.x;
  if (i < total) nsnd[i] = rsqrtf(fmaxf((float)deg[i], 1.0f));
}

// ---------------- parallel scan ---------------------------------------------
__global__ __launch_bounds__(256) void k_scan_part(const int* __restrict__ deg,
                                                   int* __restrict__ bsum, int n) {
  __shared__ int red[256];
  const int t = threadIdx.x;
  const int i = blockIdx.x * 256 + t;
  red[t] = (i < n) ? deg[i] : 0;
  __syncthreads();
  for (int off = 128; off > 0; off >>= 1) {
    if (t < off) red[t] += red[t + off];
    __syncthreads();
  }
  if (t == 0) bsum[blockIdx.x] = red[0];
}

__global__ __launch_bounds__(1024) void k_scan_mid(int* bsum, int nb) {
  __shared__ int l[1024];
  const int t = threadIdx.x;
  l[t] = (t < nb) ? bsum[t] : 0;
  __syncthreads();
  for (int off = 1; off < 1024; off <<= 1) {
    int v = l[t];
    int add = (t >= off) ? l[t - off] : 0;
    __syncthreads();
    l[t] = v + add;
    __syncthreads();
  }
  if (t < nb) bsum[t] = (t == 0) ? 0 : l[t - 1];
}

__global__ __launch_bounds__(256) void k_scan_out(const int* __restrict__ deg,
                                                  const int* __restrict__ bpre,
                                                  int* __restrict__ offsets,
                                                  int* __restrict__ cursor, int n) {
  __shared__ int l[256];
  const int t = threadIdx.x;
  const int i = blockIdx.x * 256 + t;
  const int v = (i < n) ? deg[i] : 0;
  l[t] = v;
  __syncthreads();
  for (int off = 1; off < 256; off <<= 1) {
    int x = l[t];
    int add = (t >= off) ? l[t - off] : 0;
    __syncthreads();
    l[t] = x + add;
    __syncthreads();
  }
  const int excl = bpre[blockIdx.x] + l[t] - v;
  if (i < n) {
    offsets[i] = excl;
    cursor[i] = excl;
    if (i == n - 1) offsets[n] = excl + v;
  }
}

__global__ __launch_bounds__(256) void k_fill(const int* __restrict__ src,
                                              const int* __restrict__ dst,
                                              int* cursor, int* __restrict__ csc, int E) {
  const int stride = gridDim.x * blockDim.x;
  for (int i = blockIdx.x * blockDim.x + threadIdx.x; i < E; i += stride) {
    int d = dst[i];
    int pos = atomicAdd(&cursor[d], 1);
    csc[pos] = src[i];
  }
}

// ---------------- W (fp32 KxN row-major) -> Wt (bf16, [n][k]) ----------------
__global__ __launch_bounds__(256) void k_prep_w(const float* __restrict__ W,
                                                unsigned short* __restrict__ Wt) {
  int id = blockIdx.x * 256 + threadIdx.x;
  if (id < HID * HID) {
    int nn = id >> 7, kk = id & 127;
    Wt[id] = f2bf(W[kk * HID + nn]);
  }
}

// ---------------- MFMA GEMM: Gb[row,:] = bf16( in[row,:] @ W ) ---------------
// One wave per 16-row block. B frags (full 128x128 W) in 128 VGPRs.
// F32IN: input fp32, pre-scaled by ns[row] and converted to bf16 in-kernel.
template <bool F32IN>
__global__ __launch_bounds__(256) void k_gemm_mfma(const void* __restrict__ Xin,
                                                   const unsigned short* __restrict__ Wt,
                                                   const float* __restrict__ ns,
                                                   unsigned short* __restrict__ Gb, int n) {
  __shared__ __align__(16) unsigned short stile[4][16 * 136];  // pad 128->136 vs bank conflicts
  const int wib = threadIdx.x >> 6;
  const int lane = threadIdx.x & 63;
  const int c = lane & 15;
  const int g = lane >> 4;
  const int w = blockIdx.x * 4 + wib;
  const int nrb = (n + 15) >> 4;
  const bool active = w < nrb;
  const int row0 = w * 16;

  if (active) {
    bf16x8 bfr[8][4];
#pragma unroll
    for (int ct = 0; ct < 8; ++ct)
#pragma unroll
      for (int kt = 0; kt < 4; ++kt)
        bfr[ct][kt] = *reinterpret_cast<const bf16x8*>(Wt + (ct * 16 + c) * HID + kt * 32 + g * 8);

    int arow = row0 + c;
    if (arow > n - 1) arow = n - 1;
    bf16x8 afr[4];
    if (F32IN) {
      const float* X = (const float*)Xin;
      const float sc = ns[arow];
#pragma unroll
      for (int kt = 0; kt < 4; ++kt) {
        const float* p = X + (size_t)arow * HID + kt * 32 + g * 8;
        float4 v0 = *reinterpret_cast<const float4*>(p);
        float4 v1 = *reinterpret_cast<const float4*>(p + 4);
        bf16x8 a;
        a[0] = (short)f2bf(v0.x * sc); a[1] = (short)f2bf(v0.y * sc);
        a[2] = (short)f2bf(v0.z * sc); a[3] = (short)f2bf(v0.w * sc);
        a[4] = (short)f2bf(v1.x * sc); a[5] = (short)f2bf(v1.y * sc);
        a[6] = (short)f2bf(v1.z * sc); a[7] = (short)f2bf(v1.w * sc);
        afr[kt] = a;
      }
    } else {
      const unsigned short* Xb = (const unsigned short*)Xin;
#pragma unroll
      for (int kt = 0; kt < 4; ++kt)
        afr[kt] = *reinterpret_cast<const bf16x8*>(Xb + (size_t)arow * HID + kt * 32 + g * 8);
    }

    f32x4 acc[8];
#pragma unroll
    for (int ct = 0; ct < 8; ++ct) acc[ct] = (f32x4){0.f, 0.f, 0.f, 0.f};
#pragma unroll
    for (int kt = 0; kt < 4; ++kt)
#pragma unroll
      for (int ct = 0; ct < 8; ++ct)
        acc[ct] = __builtin_amdgcn_mfma_f32_16x16x32_bf16(afr[kt], bfr[ct][kt], acc[ct], 0, 0, 0);

    // C layout: col = lane&15, row = (lane>>4)*4 + q  -> stage to LDS for coalesced store
#pragma unroll
    for (int ct = 0; ct < 8; ++ct)
#pragma unroll
      for (int q = 0; q < 4; ++q)
        stile[wib][(g * 4 + q) * 136 + ct * 16 + c] = f2bf(acc[ct][q]);
  }
  __syncthreads();
  if (active) {
#pragma unroll
    for (int p = 0; p < 4; ++p) {
      int rl = p * 4 + g;
      int grow = row0 + rl;
      if (grow < n) {
        uint4 v = *reinterpret_cast<const uint4*>(&stile[wib][rl * 136 + c * 8]);
        *reinterpret_cast<uint4*>(Gb + (size_t)grow * HID + c * 8) = v;
      }
    }
  }
}

// ---------------- gather-aggregate (bf16 in/out) + stats ---------------------
#define CHUNK 8
__global__ __launch_bounds__(256) void k_agg_finish(const unsigned short* __restrict__ H,
                                                    const int* __restrict__ offsets,
                                                    const int* __restrict__ csc,
                                                    const float* __restrict__ nd,
                                                    const float* __restrict__ bias,
                                                    unsigned short* __restrict__ OUT,
                                                    float* stats, int n) {
  const int lane = threadIdx.x & 31;  // features 4*lane .. 4*lane+3
  const int slot = threadIdx.x >> 5;  // 8 row-groups per block
  const int rstride = gridDim.x * 8;
  const float4 bj = reinterpret_cast<const float4*>(bias)[lane];
  float4 s = {0.f, 0.f, 0.f, 0.f}, sq = {0.f, 0.f, 0.f, 0.f};

  for (int i = blockIdx.x * 8 + slot; i < n; i += rstride) {
    const int e0 = offsets[i];
    const int e1 = offsets[i + 1];
    float4 acc = {0.f, 0.f, 0.f, 0.f};
    for (int e = e0; e < e1; e += CHUNK) {
      int idx[CHUNK];
#pragma unroll
      for (int k = 0; k < CHUNK; ++k) idx[k] = csc[min(e + k, e1 - 1)];
      uint2 v[CHUNK];
#pragma unroll
      for (int k = 0; k < CHUNK; ++k)
        v[k] = *reinterpret_cast<const uint2*>(H + (size_t)idx[k] * HID + lane * 4);
#pragma unroll
      for (int k = 0; k < CHUNK; ++k) {
        if (e + k < e1) {
          acc.x += bf2f((unsigned short)(v[k].x & 0xffffu));
          acc.y += bf2f((unsigned short)(v[k].x >> 16));
          acc.z += bf2f((unsigned short)(v[k].y & 0xffffu));
          acc.w += bf2f((unsigned short)(v[k].y >> 16));
        }
      }
    }
    const float ndv = nd[i];
    float4 o;
    o.x = acc.x * ndv + bj.x;
    o.y = acc.y * ndv + bj.y;
    o.z = acc.z * ndv + bj.z;
    o.w = acc.w * ndv + bj.w;
    uint2 pk;
    pk.x = (unsigned int)f2bf(o.x) | ((unsigned int)f2bf(o.y) << 16);
    pk.y = (unsigned int)f2bf(o.z) | ((unsigned int)f2bf(o.w) << 16);
    *reinterpret_cast<uint2*>(OUT + (size_t)i * HID + lane * 4) = pk;
    s.x += o.x; s.y += o.y; s.z += o.z; s.w += o.w;
    sq.x += o.x * o.x; sq.y += o.y * o.y; sq.z += o.z * o.z; sq.w += o.w * o.w;
  }

  __shared__ float red[2][8][HID];
  *reinterpret_cast<float4*>(&red[0][slot][lane * 4]) = s;
  *reinterpret_cast<float4*>(&red[1][slot][lane * 4]) = sq;
  __syncthreads();
  const int t = threadIdx.x;
  if (t < HID) {
    float a = 0.f;
#pragma unroll
    for (int k = 0; k < 8; ++k) a += red[0][k][t];
    atomicAdd(&stats[t], a);
  } else {
    const int j = t - HID;
    float a = 0.f;
#pragma unroll
    for (int k = 0; k < 8; ++k) a += red[1][k][j];
    atomicAdd(&stats[HID + j], a);
  }
}

// ---------------- BN + PReLU, bf16 in, bf16 out pre-scaled by ns -------------
__global__ __launch_bounds__(256) void k_bn_prelu_b(const unsigned short* __restrict__ IN,
                                                    unsigned short* __restrict__ OUT,
                                                    const float* __restrict__ stats,
                                                    const float* __restrict__ gamma,
                                                    const float* __restrict__ beta,
                                                    const float* __restrict__ a,
                                                    const float* __restrict__ ns,
                                                    int total4, float invN) {
  const float slope = a[0];
  const int stride = gridDim.x * blockDim.x;
  for (int i = blockIdx.x * blockDim.x + threadIdx.x; i < total4; i += stride) {
    int j4 = i & 31;
    float4 sm = reinterpret_cast<const float4*>(stats)[j4];
    float4 sqv = reinterpret_cast<const float4*>(stats + HID)[j4];
    float4 gm = reinterpret_cast<const float4*>(gamma)[j4];
    float4 bt = reinterpret_cast<const float4*>(beta)[j4];
    uint2 u = *reinterpret_cast<const uint2*>(IN + (size_t)i * 4);
    float v0 = bf2f((unsigned short)(u.x & 0xffffu));
    float v1 = bf2f((unsigned short)(u.x >> 16));
    float v2 = bf2f((unsigned short)(u.y & 0xffffu));
    float v3 = bf2f((unsigned short)(u.y >> 16));
    const float scn = ns[i >> 5];
    float m, var, t;
    m = sm.x * invN; var = sqv.x * invN - m * m;
    t = (v0 - m) * rsqrtf(var + BN_EPS) * gm.x + bt.x; v0 = (t >= 0.f ? t : slope * t) * scn;
    m = sm.y * invN; var = sqv.y * invN - m * m;
    t = (v1 - m) * rsqrtf(var + BN_EPS) * gm.y + bt.y; v1 = (t >= 0.f ? t : slope * t) * scn;
    m = sm.z * invN; var = sqv.z * invN - m * m;
    t = (v2 - m) * rsqrtf(var + BN_EPS) * gm.z + bt.z; v2 = (t >= 0.f ? t : slope * t) * scn;
    m = sm.w * invN; var = sqv.w * invN - m * m;
    t = (v3 - m) * rsqrtf(var + BN_EPS) * gm.w + bt.w; v3 = (t >= 0.f ? t : slope * t) * scn;
    uint2 pk;
    pk.x = (unsigned int)f2bf(v0) | ((unsigned int)f2bf(v1) << 16);
    pk.y = (unsigned int)f2bf(v2) | ((unsigned int)f2bf(v3) << 16);
    *reinterpret_cast<uint2*>(OUT + (size_t)i * 4) = pk;
  }
}

// ---------------- BN + PReLU, bf16 in, fp32 out (final) ----------------------
__global__ __launch_bounds__(256) void k_bn_prelu_f(const unsigned short* __restrict__ IN,
                                                    float* __restrict__ OUT,
                                                    const float* __restrict__ stats,
                                                    const float* __restrict__ gamma,
                                                    const float* __restrict__ beta,
                                                    const float* __restrict__ a,
                                                    int total4, float invN) {
  const float slope = a[0];
  const int stride = gridDim.x * blockDim.x;
  for (int i = blockIdx.x * blockDim.x + threadIdx.x; i < total4; i += stride) {
    int j4 = i & 31;
    float4 sm = reinterpret_cast<const float4*>(stats)[j4];
    float4 sqv = reinterpret_cast<const float4*>(stats + HID)[j4];
    float4 gm = reinterpret_cast<const float4*>(gamma)[j4];
    float4 bt = reinterpret_cast<const float4*>(beta)[j4];
    uint2 u = *reinterpret_cast<const uint2*>(IN + (size_t)i * 4);
    float4 o;
    float m, var, t;
    m = sm.x * invN; var = sqv.x * invN - m * m;
    t = (bf2f((unsigned short)(u.x & 0xffffu)) - m) * rsqrtf(var + BN_EPS) * gm.x + bt.x;
    o.x = t >= 0.f ? t : slope * t;
    m = sm.y * invN; var = sqv.y * invN - m * m;
    t = (bf2f((unsigned short)(u.x >> 16)) - m) * rsqrtf(var + BN_EPS) * gm.y + bt.y;
    o.y = t >= 0.f ? t : slope * t;
    m = sm.z * invN; var = sqv.z * invN - m * m;
    t = (bf2f((unsigned short)(u.y & 0xffffu)) - m) * rsqrtf(var + BN_EPS) * gm.z + bt.z;
    o.z = t >= 0.f ? t : slope * t;
    m = sm.w * invN; var = sqv.w * invN - m * m;
    t = (bf2f((unsigned short)(u.y >> 16)) - m) * rsqrtf(var + BN_EPS) * gm.w + bt.w;
    o.w = t >= 0.f ? t : slope * t;
    reinterpret_cast<float4*>(OUT)[i] = o;
  }
}

extern "C" void kernel_launch(void* const* d_in, const int* in_sizes, int n_in,
                              void* d_out, int out_size, void* d_ws, size_t ws_size,
                              hipStream_t stream) {
  const float* X   = (const float*)d_in[0];
  const float* W1  = (const float*)d_in[1];
  const float* b1  = (const float*)d_in[2];
  const float* g1  = (const float*)d_in[3];
  const float* be1 = (const float*)d_in[4];
  const float* a1  = (const float*)d_in[5];
  const float* W2  = (const float*)d_in[6];
  const float* b2  = (const float*)d_in[7];
  const float* g2  = (const float*)d_in[8];
  const float* be2 = (const float*)d_in[9];
  const float* a2  = (const float*)d_in[10];
  const int*   ei  = (const int*)d_in[11];

  const int N = in_sizes[0] / HID;
  const int E = in_sizes[11] / 2;
  const int* src = ei;
  const int* dst = ei + E;

  float* out = (float*)d_out;

  // workspace layout (<= previous footprint ~29 MB)
  unsigned short* bufA = (unsigned short*)d_ws;            // N*128 bf16
  unsigned short* bufB = bufA + (size_t)N * HID;           // N*128 bf16
  int*   deg     = (int*)(bufB + (size_t)N * HID);         // 2N ints
  float* NSND    = (float*)(deg + 2 * (size_t)N);          // 2N floats (NS then ND)
  float* ST      = NSND + 2 * (size_t)N;                   // 512 floats
  int*   offsets = (int*)(ST + 512);                       // N+1
  int*   csc     = offsets + N + 1;                        // E
  int*   bsum    = csc + E;                                // <=1024
  unsigned short* Wt1 = (unsigned short*)(bsum + 1024);    // 128*128 bf16
  unsigned short* Wt2 = Wt1 + HID * HID;                   // 128*128 bf16
  int*   cursor  = deg;                                    // alias out-deg (free after k_norm)

  const float invN = 1.0f / (float)N;
  const int total4 = N * (HID / 4);
  const int nb = (N + 255) / 256;
  const int gemmgrid = ((N + 15) / 16 + 3) / 4;

  hipMemsetAsync(deg, 0, 2 * (size_t)N * sizeof(int), stream);
  hipMemsetAsync(ST, 0, 512 * sizeof(float), stream);

  // graph preprocessing + weight prep (once)
  k_hist<<<1024, 256, 0, stream>>>(src, dst, deg, E, N);
  k_norm<<<(2 * N + 255) / 256, 256, 0, stream>>>(deg, NSND, 2 * N);
  k_scan_part<<<nb, 256, 0, stream>>>(deg + N, bsum, N);
  k_scan_mid<<<1, 1024, 0, stream>>>(bsum, nb);
  k_scan_out<<<nb, 256, 0, stream>>>(deg + N, bsum, offsets, cursor, N);
  k_fill<<<1024, 256, 0, stream>>>(src, dst, cursor, csc, E);
  k_prep_w<<<(HID * HID + 255) / 256, 256, 0, stream>>>(W1, Wt1);
  k_prep_w<<<(HID * HID + 255) / 256, 256, 0, stream>>>(W2, Wt2);

  // ---- layer 1 ----
  k_gemm_mfma<true><<<gemmgrid, 256, 0, stream>>>(X, Wt1, NSND, bufA, N);
  k_agg_finish<<<1024, 256, 0, stream>>>(bufA, offsets, csc, NSND + N, b1, bufB, ST, N);
  k_bn_prelu_b<<<2048, 256, 0, stream>>>(bufB, bufA, ST, g1, be1, a1, NSND, total4, invN);

  // ---- layer 2 ----
  k_gemm_mfma<false><<<gemmgrid, 256, 0, stream>>>(bufA, Wt2, nullptr, bufB, N);
  k_agg_finish<<<1024, 256, 0, stream>>>(bufB, offsets, csc, NSND + N, b2, bufA, ST + 256, N);
  k_bn_prelu_f<<<2048, 256, 0, stream>>>(bufA, out, ST + 256, g2, be2, a2, total4, invN);
}

// Round 6
// 279.873 us; speedup vs baseline: 3.1338x; 1.0409x over previous
//
#include <hip/hip_runtime.h>

#define HID 128
#define BN_EPS 1e-5f

typedef __attribute__((ext_vector_type(8))) short bf16x8;
typedef __attribute__((ext_vector_type(4))) float f32x4;

__device__ __forceinline__ float bf2f(unsigned short u) {
  union { unsigned int i; float f; } c; c.i = ((unsigned int)u) << 16; return c.f;
}
__device__ __forceinline__ unsigned short f2bf(float f) {
  union { float f; unsigned int i; } c; c.f = f;
  unsigned int u = c.i;
  return (unsigned short)((u + 0x7FFFu + ((u >> 16) & 1u)) >> 16);
}
__device__ __forceinline__ void unpack8(uint4 u, float* f) {
  f[0] = bf2f((unsigned short)(u.x & 0xffffu)); f[1] = bf2f((unsigned short)(u.x >> 16));
  f[2] = bf2f((unsigned short)(u.y & 0xffffu)); f[3] = bf2f((unsigned short)(u.y >> 16));
  f[4] = bf2f((unsigned short)(u.z & 0xffffu)); f[5] = bf2f((unsigned short)(u.z >> 16));
  f[6] = bf2f((unsigned short)(u.w & 0xffffu)); f[7] = bf2f((unsigned short)(u.w >> 16));
}
__device__ __forceinline__ uint4 pack8(const float* f) {
  uint4 u;
  u.x = (unsigned int)f2bf(f[0]) | ((unsigned int)f2bf(f[1]) << 16);
  u.y = (unsigned int)f2bf(f[2]) | ((unsigned int)f2bf(f[3]) << 16);
  u.z = (unsigned int)f2bf(f[4]) | ((unsigned int)f2bf(f[5]) << 16);
  u.w = (unsigned int)f2bf(f[6]) | ((unsigned int)f2bf(f[7]) << 16);
  return u;
}

// ---------------- degree histogram ------------------------------------------
__global__ __launch_bounds__(256) void k_hist(const int* __restrict__ src,
                                              const int* __restrict__ dst,
                                              int* deg, int E, int N) {
  const int stride = gridDim.x * blockDim.x;
  for (int i = blockIdx.x * blockDim.x + threadIdx.x; i < E; i += stride) {
    atomicAdd(&deg[src[i]], 1);
    atomicAdd(&deg[N + dst[i]], 1);
  }
}

__global__ __launch_bounds__(256) void k_norm(const int* __restrict__ deg,
                                              float* __restrict__ nsnd, int total) {
  int i = blockIdx.x * blockDim.x + threadIdx.x;
  if (i < total) nsnd[i] = rsqrtf(fmaxf((float)deg[i], 1.0f));
}

// ---------------- parallel scan ---------------------------------------------
__global__ __launch_bounds__(256) void k_scan_part(const int* __restrict__ deg,
                                                   int* __restrict__ bsum, int n) {
  __shared__ int red[256];
  const int t = threadIdx.x;
  const int i = blockIdx.x * 256 + t;
  red[t] = (i < n) ? deg[i] : 0;
  __syncthreads();
  for (int off = 128; off > 0; off >>= 1) {
    if (t < off) red[t] += red[t + off];
    __syncthreads();
  }
  if (t == 0) bsum[blockIdx.x] = red[0];
}

__global__ __launch_bounds__(1024) void k_scan_mid(int* bsum, int nb) {
  __shared__ int l[1024];
  const int t = threadIdx.x;
  l[t] = (t < nb) ? bsum[t] : 0;
  __syncthreads();
  for (int off = 1; off < 1024; off <<= 1) {
    int v = l[t];
    int add = (t >= off) ? l[t - off] : 0;
    __syncthreads();
    l[t] = v + add;
    __syncthreads();
  }
  if (t < nb) bsum[t] = (t == 0) ? 0 : l[t - 1];
}

__global__ __launch_bounds__(256) void k_scan_out(const int* __restrict__ deg,
                                                  const int* __restrict__ bpre,
                                                  int* __restrict__ offsets,
                                                  int* __restrict__ cursor, int n) {
  __shared__ int l[256];
  const int t = threadIdx.x;
  const int i = blockIdx.x * 256 + t;
  const int v = (i < n) ? deg[i] : 0;
  l[t] = v;
  __syncthreads();
  for (int off = 1; off < 256; off <<= 1) {
    int x = l[t];
    int add = (t >= off) ? l[t - off] : 0;
    __syncthreads();
    l[t] = x + add;
    __syncthreads();
  }
  const int excl = bpre[blockIdx.x] + l[t] - v;
  if (i < n) {
    offsets[i] = excl;
    cursor[i] = excl;
    if (i == n - 1) offsets[n] = excl + v;
  }
}

__global__ __launch_bounds__(256) void k_fill(const int* __restrict__ src,
                                              const int* __restrict__ dst,
                                              int* cursor, int* __restrict__ csc, int E) {
  const int stride = gridDim.x * blockDim.x;
  for (int i = blockIdx.x * blockDim.x + threadIdx.x; i < E; i += stride) {
    int d = dst[i];
    int pos = atomicAdd(&cursor[d], 1);
    csc[pos] = src[i];
  }
}

// ---------------- W (fp32 KxN row-major) -> Wt (bf16, [n][k]) ----------------
__global__ __launch_bounds__(256) void k_prep_w(const float* __restrict__ W,
                                                unsigned short* __restrict__ Wt) {
  int id = blockIdx.x * 256 + threadIdx.x;
  if (id < HID * HID) {
    int nn = id >> 7, kk = id & 127;
    Wt[id] = f2bf(W[kk * HID + nn]);
  }
}

// ---------------- per-feature BN params: scale = g*rsqrt(var+eps), shift = b - m*scale
__global__ __launch_bounds__(128) void k_bnparams(const float* __restrict__ ST,
                                                  const float* __restrict__ gamma,
                                                  const float* __restrict__ beta,
                                                  float* __restrict__ PS,
                                                  float* __restrict__ PH, float invN) {
  const int t = threadIdx.x;
  float m = ST[t] * invN;
  float var = ST[HID + t] * invN - m * m;
  float sc = gamma[t] * rsqrtf(var + BN_EPS);
  PS[t] = sc;
  PH[t] = beta[t] - m * sc;
}

// ---------------- MFMA GEMM: Gb[row,:] = bf16( A[row,:] @ W ) ----------------
// MODE 0: A = fp32 X * ns[row].  MODE 1: A = prelu(bf16 X * PS + PH) * ns[row].
// One wave per 16-row block, grid-stride over blocks; W frags resident in VGPRs.
// Per-wave LDS repack tile -> no block barrier needed.
template <int MODE>
__global__ __launch_bounds__(256) void k_gemm_mfma(const void* __restrict__ Xin,
                                                   const unsigned short* __restrict__ Wt,
                                                   const float* __restrict__ ns,
                                                   const float* __restrict__ PS,
                                                   const float* __restrict__ PH,
                                                   const float* __restrict__ aslope,
                                                   unsigned short* __restrict__ Gb, int n) {
  __shared__ __align__(16) unsigned short stile[4][16 * 136];
  const int wib = threadIdx.x >> 6;
  const int lane = threadIdx.x & 63;
  const int c = lane & 15;
  const int g = lane >> 4;
  const int nrb = (n + 15) >> 4;
  const int nw = gridDim.x * 4;

  bf16x8 bfr[8][4];
#pragma unroll
  for (int ct = 0; ct < 8; ++ct)
#pragma unroll
    for (int kt = 0; kt < 4; ++kt)
      bfr[ct][kt] = *reinterpret_cast<const bf16x8*>(Wt + (ct * 16 + c) * HID + kt * 32 + g * 8);

  const float slope = (MODE == 1) ? aslope[0] : 0.f;

  for (int w = blockIdx.x * 4 + wib; w < nrb; w += nw) {
    const int row0 = w * 16;
    int arow = row0 + c;
    if (arow > n - 1) arow = n - 1;
    const float sc = ns[arow];
    bf16x8 afr[4];
    if (MODE == 0) {
      const float* X = (const float*)Xin;
#pragma unroll
      for (int kt = 0; kt < 4; ++kt) {
        const float* p = X + (size_t)arow * HID + kt * 32 + g * 8;
        float4 v0 = *reinterpret_cast<const float4*>(p);
        float4 v1 = *reinterpret_cast<const float4*>(p + 4);
        bf16x8 a;
        a[0] = (short)f2bf(v0.x * sc); a[1] = (short)f2bf(v0.y * sc);
        a[2] = (short)f2bf(v0.z * sc); a[3] = (short)f2bf(v0.w * sc);
        a[4] = (short)f2bf(v1.x * sc); a[5] = (short)f2bf(v1.y * sc);
        a[6] = (short)f2bf(v1.z * sc); a[7] = (short)f2bf(v1.w * sc);
        afr[kt] = a;
      }
    } else {
      const unsigned short* Xb = (const unsigned short*)Xin;
#pragma unroll
      for (int kt = 0; kt < 4; ++kt) {
        const int k0 = kt * 32 + g * 8;
        uint4 u = *reinterpret_cast<const uint4*>(Xb + (size_t)arow * HID + k0);
        float f[8];
        unpack8(u, f);
        float4 s0 = *reinterpret_cast<const float4*>(PS + k0);
        float4 s1 = *reinterpret_cast<const float4*>(PS + k0 + 4);
        float4 h0 = *reinterpret_cast<const float4*>(PH + k0);
        float4 h1 = *reinterpret_cast<const float4*>(PH + k0 + 4);
        float t;
        t = fmaf(f[0], s0.x, h0.x); f[0] = (t >= 0.f ? t : slope * t) * sc;
        t = fmaf(f[1], s0.y, h0.y); f[1] = (t >= 0.f ? t : slope * t) * sc;
        t = fmaf(f[2], s0.z, h0.z); f[2] = (t >= 0.f ? t : slope * t) * sc;
        t = fmaf(f[3], s0.w, h0.w); f[3] = (t >= 0.f ? t : slope * t) * sc;
        t = fmaf(f[4], s1.x, h1.x); f[4] = (t >= 0.f ? t : slope * t) * sc;
        t = fmaf(f[5], s1.y, h1.y); f[5] = (t >= 0.f ? t : slope * t) * sc;
        t = fmaf(f[6], s1.z, h1.z); f[6] = (t >= 0.f ? t : slope * t) * sc;
        t = fmaf(f[7], s1.w, h1.w); f[7] = (t >= 0.f ? t : slope * t) * sc;
        bf16x8 a;
        a[0] = (short)f2bf(f[0]); a[1] = (short)f2bf(f[1]);
        a[2] = (short)f2bf(f[2]); a[3] = (short)f2bf(f[3]);
        a[4] = (short)f2bf(f[4]); a[5] = (short)f2bf(f[5]);
        a[6] = (short)f2bf(f[6]); a[7] = (short)f2bf(f[7]);
        afr[kt] = a;
      }
    }

    f32x4 acc[8];
#pragma unroll
    for (int ct = 0; ct < 8; ++ct) acc[ct] = (f32x4){0.f, 0.f, 0.f, 0.f};
#pragma unroll
    for (int kt = 0; kt < 4; ++kt)
#pragma unroll
      for (int ct = 0; ct < 8; ++ct)
        acc[ct] = __builtin_amdgcn_mfma_f32_16x16x32_bf16(afr[kt], bfr[ct][kt], acc[ct], 0, 0, 0);

    // C layout: col = lane&15, row = (lane>>4)*4 + q  (per-wave LDS tile repack)
#pragma unroll
    for (int ct = 0; ct < 8; ++ct)
#pragma unroll
      for (int q = 0; q < 4; ++q)
        stile[wib][(g * 4 + q) * 136 + ct * 16 + c] = f2bf(acc[ct][q]);

#pragma unroll
    for (int p = 0; p < 4; ++p) {
      int rl = p * 4 + g;
      int grow = row0 + rl;
      if (grow < n) {
        uint4 v = *reinterpret_cast<const uint4*>(&stile[wib][rl * 136 + c * 8]);
        *reinterpret_cast<uint4*>(Gb + (size_t)grow * HID + c * 8) = v;
      }
    }
  }
}

// ---------------- gather-aggregate (bf16 in/out) + stats ---------------------
// 16 lanes/row (uint4 = 8 bf16 each), 16 row-slots per 256-block, CHUNK-deep MLP.
#define CHUNK 8
__global__ __launch_bounds__(256) void k_agg_finish(const unsigned short* __restrict__ H,
                                                    const int* __restrict__ offsets,
                                                    const int* __restrict__ csc,
                                                    const float* __restrict__ nd,
                                                    const float* __restrict__ bias,
                                                    unsigned short* __restrict__ OUT,
                                                    float* stats, int n) {
  const int lane = threadIdx.x & 15;  // features 8*lane .. 8*lane+7
  const int slot = threadIdx.x >> 4;  // 16 row-slots per block
  const int rstride = gridDim.x * 16;
  const float4 bj0 = reinterpret_cast<const float4*>(bias)[lane * 2];
  const float4 bj1 = reinterpret_cast<const float4*>(bias)[lane * 2 + 1];
  float s[8] = {0.f, 0.f, 0.f, 0.f, 0.f, 0.f, 0.f, 0.f};
  float sq[8] = {0.f, 0.f, 0.f, 0.f, 0.f, 0.f, 0.f, 0.f};

  for (int i = blockIdx.x * 16 + slot; i < n; i += rstride) {
    const int e0 = offsets[i];
    const int e1 = offsets[i + 1];
    float acc[8] = {0.f, 0.f, 0.f, 0.f, 0.f, 0.f, 0.f, 0.f};
    for (int e = e0; e < e1; e += CHUNK) {
      int idx[CHUNK];
#pragma unroll
      for (int k = 0; k < CHUNK; ++k) idx[k] = csc[min(e + k, e1 - 1)];
      uint4 v[CHUNK];
#pragma unroll
      for (int k = 0; k < CHUNK; ++k)
        v[k] = *reinterpret_cast<const uint4*>(H + (size_t)idx[k] * HID + lane * 8);
#pragma unroll
      for (int k = 0; k < CHUNK; ++k) {
        if (e + k < e1) {
          float f[8];
          unpack8(v[k], f);
#pragma unroll
          for (int j = 0; j < 8; ++j) acc[j] += f[j];
        }
      }
    }
    const float ndv = nd[i];
    float o[8];
    o[0] = acc[0] * ndv + bj0.x; o[1] = acc[1] * ndv + bj0.y;
    o[2] = acc[2] * ndv + bj0.z; o[3] = acc[3] * ndv + bj0.w;
    o[4] = acc[4] * ndv + bj1.x; o[5] = acc[5] * ndv + bj1.y;
    o[6] = acc[6] * ndv + bj1.z; o[7] = acc[7] * ndv + bj1.w;
    *reinterpret_cast<uint4*>(OUT + (size_t)i * HID + lane * 8) = pack8(o);
#pragma unroll
    for (int j = 0; j < 8; ++j) { s[j] += o[j]; sq[j] += o[j] * o[j]; }
  }

  __shared__ float red[2][16][HID];  // 16 KB
  *reinterpret_cast<float4*>(&red[0][slot][lane * 8]) = (float4){s[0], s[1], s[2], s[3]};
  *reinterpret_cast<float4*>(&red[0][slot][lane * 8 + 4]) = (float4){s[4], s[5], s[6], s[7]};
  *reinterpret_cast<float4*>(&red[1][slot][lane * 8]) = (float4){sq[0], sq[1], sq[2], sq[3]};
  *reinterpret_cast<float4*>(&red[1][slot][lane * 8 + 4]) = (float4){sq[4], sq[5], sq[6], sq[7]};
  __syncthreads();
  const int t = threadIdx.x;
  if (t < HID) {
    float a = 0.f;
#pragma unroll
    for (int k = 0; k < 16; ++k) a += red[0][k][t];
    atomicAdd(&stats[t], a);
  } else {
    const int j = t - HID;
    float a = 0.f;
#pragma unroll
    for (int k = 0; k < 16; ++k) a += red[1][k][j];
    atomicAdd(&stats[HID + j], a);
  }
}

// ---------------- final BN + PReLU (bf16 in, fp32 out) via precomputed params
__global__ __launch_bounds__(256) void k_bn_final(const unsigned short* __restrict__ IN,
                                                  float* __restrict__ OUT,
                                                  const float* __restrict__ PS,
                                                  const float* __restrict__ PH,
                                                  const float* __restrict__ a, int total4) {
  const float slope = a[0];
  const int stride = gridDim.x * blockDim.x;
  for (int i = blockIdx.x * blockDim.x + threadIdx.x; i < total4; i += stride) {
    int j4 = i & 31;
    float4 ps = reinterpret_cast<const float4*>(PS)[j4];
    float4 ph = reinterpret_cast<const float4*>(PH)[j4];
    uint2 u = *reinterpret_cast<const uint2*>(IN + (size_t)i * 4);
    float4 o;
    float t;
    t = fmaf(bf2f((unsigned short)(u.x & 0xffffu)), ps.x, ph.x); o.x = t >= 0.f ? t : slope * t;
    t = fmaf(bf2f((unsigned short)(u.x >> 16)),     ps.y, ph.y); o.y = t >= 0.f ? t : slope * t;
    t = fmaf(bf2f((unsigned short)(u.y & 0xffffu)), ps.z, ph.z); o.z = t >= 0.f ? t : slope * t;
    t = fmaf(bf2f((unsigned short)(u.y >> 16)),     ps.w, ph.w); o.w = t >= 0.f ? t : slope * t;
    reinterpret_cast<float4*>(OUT)[i] = o;
  }
}

extern "C" void kernel_launch(void* const* d_in, const int* in_sizes, int n_in,
                              void* d_out, int out_size, void* d_ws, size_t ws_size,
                              hipStream_t stream) {
  const float* X   = (const float*)d_in[0];
  const float* W1  = (const float*)d_in[1];
  const float* b1  = (const float*)d_in[2];
  const float* g1  = (const float*)d_in[3];
  const float* be1 = (const float*)d_in[4];
  const float* a1  = (const float*)d_in[5];
  const float* W2  = (const float*)d_in[6];
  const float* b2  = (const float*)d_in[7];
  const float* g2  = (const float*)d_in[8];
  const float* be2 = (const float*)d_in[9];
  const float* a2  = (const float*)d_in[10];
  const int*   ei  = (const int*)d_in[11];

  const int N = in_sizes[0] / HID;
  const int E = in_sizes[11] / 2;
  const int* src = ei;
  const int* dst = ei + E;

  float* out = (float*)d_out;

  // workspace layout
  unsigned short* bufA = (unsigned short*)d_ws;            // N*128 bf16
  unsigned short* bufB = bufA + (size_t)N * HID;           // N*128 bf16
  int*   deg     = (int*)(bufB + (size_t)N * HID);         // 2N ints
  float* NSND    = (float*)(deg + 2 * (size_t)N);          // 2N floats (NS then ND)
  float* ST      = NSND + 2 * (size_t)N;                   // 512 floats (2 layers)
  int*   offsets = (int*)(ST + 512);                       // N+1
  int*   csc     = offsets + N + 1;                        // E
  int*   bsum    = csc + E;                                // <=1024
  unsigned short* Wt1 = (unsigned short*)(bsum + 1024);    // 128*128 bf16
  unsigned short* Wt2 = Wt1 + HID * HID;                   // 128*128 bf16
  float* PS1 = (float*)(Wt2 + HID * HID);                  // 128
  float* PH1 = PS1 + HID;                                  // 128
  float* PS2 = PH1 + HID;                                  // 128
  float* PH2 = PS2 + HID;                                  // 128
  int*   cursor  = deg;                                    // alias out-deg

  const float invN = 1.0f / (float)N;
  const int nb = (N + 255) / 256;

  hipMemsetAsync(deg, 0, 2 * (size_t)N * sizeof(int), stream);
  hipMemsetAsync(ST, 0, 512 * sizeof(float), stream);

  // graph preprocessing + weight prep (once)
  k_hist<<<1024, 256, 0, stream>>>(src, dst, deg, E, N);
  k_norm<<<(2 * N + 255) / 256, 256, 0, stream>>>(deg, NSND, 2 * N);
  k_scan_part<<<nb, 256, 0, stream>>>(deg + N, bsum, N);
  k_scan_mid<<<1, 1024, 0, stream>>>(bsum, nb);
  k_scan_out<<<nb, 256, 0, stream>>>(deg + N, bsum, offsets, cursor, N);
  k_fill<<<1024, 256, 0, stream>>>(src, dst, cursor, csc, E);
  k_prep_w<<<(HID * HID + 255) / 256, 256, 0, stream>>>(W1, Wt1);
  k_prep_w<<<(HID * HID + 255) / 256, 256, 0, stream>>>(W2, Wt2);

  // ---- layer 1 ----
  k_gemm_mfma<0><<<512, 256, 0, stream>>>(X, Wt1, NSND, nullptr, nullptr, nullptr, bufA, N);
  k_agg_finish<<<2048, 256, 0, stream>>>(bufA, offsets, csc, NSND + N, b1, bufB, ST, N);
  k_bnparams<<<1, 128, 0, stream>>>(ST, g1, be1, PS1, PH1, invN);

  // ---- layer 2 (BN1+PReLU1+ns fused into GEMM A-path) ----
  k_gemm_mfma<1><<<512, 256, 0, stream>>>(bufB, Wt2, NSND, PS1, PH1, a1, bufA, N);
  k_agg_finish<<<2048, 256, 0, stream>>>(bufA, offsets, csc, NSND + N, b2, bufB, ST + 256, N);
  k_bnparams<<<1, 128, 0, stream>>>(ST + 256, g2, be2, PS2, PH2, invN);
  k_bn_final<<<2048, 256, 0, stream>>>(bufB, out, PS2, PH2, a2, N * (HID / 4));
}